// Round 2
// baseline (219.171 us; speedup 1.0000x reference)
//
#include <hip/hip_runtime.h>

// RAConv: reciprocal-attention graph conv, N=100K nodes, E=1.6M edges, D=64, fp32.
// CSR build -> wave-per-node register gather -> bf16 MFMA GEMM.
//   msg = (sum_e x_src*exp(logit)) / (sum_e exp(logit));  var = E[x^2]-E[x]^2
// R2-R10: see git log (split-half gather, MFMA gemm, XCD partition, bf16
//        datapath, rank-recording hist, atomic-free scatter, pipelined loads,
//        pk-fp32 accum, 4-way scatter partitions, fused cast+hist).
// R11: global-atomic-free CSR build (2-level LDS bucket sort): hist ->
//      2-level scan -> part (packed (src<<8)|dst&255) -> per-bucket fsort.
// R12: node_gather latency pipeline. Old loop chained srcs load -> xb gather
//      serially per 8-edge batch (~800cy chain vs ~600cy of other-wave cover,
//      VALUBusy 73%). Now: (a) srcs preloaded 64/chunk into lane regs, batch
//      indices via __shfl (ds_bpermute, no global); (b) xb row gather double-
//      buffered one batch ahead; (c) exp(t/8) folded to exp2(t*0.18034).

static inline size_t ws_align(size_t x) { return (x + 255) & ~size_t(255); }

typedef __attribute__((ext_vector_type(8))) short bf16x8;
typedef __attribute__((ext_vector_type(4))) float f32x4;
typedef __attribute__((ext_vector_type(2))) float f32x2;

#define ECHUNK 4096   // edges per histogram/partition block

__device__ __forceinline__ unsigned short f2bf(float f) {
    unsigned u = __builtin_bit_cast(unsigned, f);
    u += 0x7FFFu + ((u >> 16) & 1u);          // RNE
    return (unsigned short)(u >> 16);
}
__device__ __forceinline__ float bfhi(int d) {          // high bf16 of dword
    return __builtin_bit_cast(float, (unsigned)d & 0xFFFF0000u);
}
__device__ __forceinline__ float bflo(int d) {          // low bf16 of dword
    return __builtin_bit_cast(float, (unsigned)d << 16);
}

// exp(t*0.125) == exp2(t*0.125*log2(e))
#define EXP_SCALE 0.18033688f
__device__ __forceinline__ float fast_exp8(float t) {
#if __has_builtin(__builtin_amdgcn_exp2f)
    return __builtin_amdgcn_exp2f(t * EXP_SCALE);
#else
    return __expf(t * 0.125f);
#endif
}

// Fused: cast x->bf16 (grid-stride) AND per-chunk LDS histogram over coarse
// buckets (dst>>8). Block b owns edges [b*ECHUNK, (b+1)*ECHUNK); writes
// hist[bucket*nblk + b] (bucket-major so bucket segments are contiguous
// after the scan). No global atomics.
__global__ void __launch_bounds__(256) hist_cast_kernel(
        const float* __restrict__ x, unsigned short* __restrict__ xb,
        const int* __restrict__ ei, int* __restrict__ hist,
        int E, int n4, int nblk, int nb1) {
    __shared__ int h[512];                       // nb1 <= 512 (N <= 131072)
    for (int k = threadIdx.x; k < nb1; k += 256) h[k] = 0;
    // cast part: grid-stride over n4 float4s
    int stride = gridDim.x * 256;
    for (int i = blockIdx.x * 256 + threadIdx.x; i < n4; i += stride) {
        float4 v = ((const float4*)x)[i];
        ushort4 hh; hh.x = f2bf(v.x); hh.y = f2bf(v.y); hh.z = f2bf(v.z); hh.w = f2bf(v.w);
        ((ushort4*)xb)[i] = hh;
    }
    __syncthreads();
    const int* dstp = ei + E;
    int base = blockIdx.x * ECHUNK;
    #pragma unroll 4
    for (int k = 0; k < ECHUNK / 256; ++k) {
        int e = base + k * 256 + threadIdx.x;
        if (e < E) atomicAdd(&h[dstp[e] >> 8], 1);
    }
    __syncthreads();
    for (int k = threadIdx.x; k < nb1; k += 256) hist[k * nblk + blockIdx.x] = h[k];
}

// Exclusive scan over M = nb1*nblk counts, in place, 256/block; block sums out.
__global__ void scan_a_kernel(int* __restrict__ h, int* __restrict__ bsum, int M) {
    __shared__ int t[256];
    int i = blockIdx.x * 256 + threadIdx.x;
    int v = (i < M) ? h[i] : 0;
    t[threadIdx.x] = v;
    __syncthreads();
    for (int off = 1; off < 256; off <<= 1) {
        int u = (threadIdx.x >= (unsigned)off) ? t[threadIdx.x - off] : 0;
        __syncthreads();
        t[threadIdx.x] += u;
        __syncthreads();
    }
    if (i < M) h[i] = t[threadIdx.x] - v;        // exclusive within block
    if (threadIdx.x == 255) bsum[blockIdx.x] = t[255];
}

// Exclusive scan of block sums (nb <= 1024). Consumers add bsum[idx>>8].
__global__ void scan_b_kernel(int* __restrict__ bsum, int nb) {
    __shared__ int t[1024];
    int i = threadIdx.x;
    int v = (i < nb) ? bsum[i] : 0;
    t[i] = v;
    __syncthreads();
    for (int off = 1; off < 1024; off <<= 1) {
        int u = (i >= off) ? t[i - off] : 0;
        __syncthreads();
        t[i] += u;
        __syncthreads();
    }
    if (i < nb) bsum[i] = t[i] - v;             // exclusive
}

// Partition edges into coarse-bucket segments. Block b re-reads its chunk,
// ranks via LDS atomics on its scanned offsets, writes packed
// (src<<8)|(dst&255) -- src < 2^17, key 8 bits -> fits int.
__global__ void __launch_bounds__(256) part_kernel(
        const int* __restrict__ ei, const int* __restrict__ offs,
        const int* __restrict__ bsum, int* __restrict__ tmp,
        int E, int nblk, int nb1) {
    __shared__ int lofs[512];
    int b = blockIdx.x;
    for (int k = threadIdx.x; k < nb1; k += 256) {
        int idx = k * nblk + b;
        lofs[k] = offs[idx] + bsum[idx >> 8];
    }
    __syncthreads();
    const int* dstp = ei + E;
    int base = b * ECHUNK;
    #pragma unroll 4
    for (int k = 0; k < ECHUNK / 256; ++k) {
        int e = base + k * 256 + threadIdx.x;
        if (e < E) {
            int dst = dstp[e];
            int src = ei[e];
            int pos = atomicAdd(&lofs[dst >> 8], 1);
            tmp[pos] = (src << 8) | (dst & 255);
        }
    }
}

// Per-bucket fine sort: one block per bucket (256 nodes <-> 256 threads).
// LDS 256-bin hist + scan -> writes rs[node] directly, scatters srcs in CSR
// order via LDS-atomic ranks.
__global__ void __launch_bounds__(256) fsort_kernel(
        const int* __restrict__ tmp, const int* __restrict__ offs,
        const int* __restrict__ bsum, int* __restrict__ srcs,
        int* __restrict__ rs, int E, int N, int nblk, int nb1) {
    __shared__ int cnt[256], sc[256], lofs[256];
    int b = blockIdx.x, tid = threadIdx.x;
    int i0 = b * nblk;
    int start = offs[i0] + bsum[i0 >> 8];
    int end;
    if (b == nb1 - 1) end = E;
    else { int i1 = (b + 1) * nblk; end = offs[i1] + bsum[i1 >> 8]; }

    cnt[tid] = 0;
    __syncthreads();
    for (int e = start + tid; e < end; e += 256) atomicAdd(&cnt[tmp[e] & 255], 1);
    __syncthreads();
    int c = cnt[tid];
    sc[tid] = c;
    __syncthreads();
    for (int off = 1; off < 256; off <<= 1) {
        int u = (tid >= off) ? sc[tid - off] : 0;
        __syncthreads();
        sc[tid] += u;
        __syncthreads();
    }
    int excl = sc[tid] - c;
    int node = b * 256 + tid;
    if (node < N) rs[node] = start + excl;
    lofs[tid] = start + excl;
    __syncthreads();
    for (int e = start + tid; e < end; e += 256) {
        int v = tmp[e];
        int pos = atomicAdd(&lofs[v & 255], 1);
        srcs[pos] = v >> 8;
    }
    if (b == 0 && tid == 0) rs[N] = E;
}

// One wave per node, 4 edges per batch: 16-lane group g handles one edge,
// lane q=lane&15 holds features 4q..4q+3 as two float2 (packed-fp32 path).
// R12: srcs for a <=64-edge chunk preloaded into lane registers (one
// coalesced load); per-batch indices via __shfl (ds_bpermute). xb row
// gathers double-buffered one 8-edge batch ahead.
__global__ void __launch_bounds__(256) node_gather_kernel(
        const unsigned short* __restrict__ xb,
        const int* __restrict__ rs, const int* __restrict__ srcs,
        unsigned short* __restrict__ msgvar, int N) {
    int w = (blockIdx.x * blockDim.x + threadIdx.x) >> 6;
    if (w >= N) return;
    int lane = threadIdx.x & 63;
    int q = lane & 15;                 // feature block (features 4q..4q+3)
    int g = lane >> 4;                 // edge slot within batch of 4
    int s = rs[w], e = rs[w + 1];
    const int2* xb2 = (const int2*)xb;            // row = 16 int2 (128 B)
    int2 dn = xb2[(size_t)w * 16 + q];
    f32x2 xn01 = {bflo(dn.x), bfhi(dn.x)}, xn23 = {bflo(dn.y), bfhi(dn.y)};
    float den = 0.f;
    f32x2 sxa = {0,0}, sxb = {0,0}, ssqa = {0,0}, ssqb = {0,0},
          smea = {0,0}, smeb = {0,0};

    auto compute = [&](int2 d) {
        f32x2 a = {bflo(d.x), bfhi(d.x)};
        f32x2 b = {bflo(d.y), bfhi(d.y)};
        f32x2 dp = a * xn01 + b * xn23;           // pk mul + pk fma
        float t = dp.x + dp.y;
        #pragma unroll
        for (int off = 1; off < 16; off <<= 1) t += __shfl_xor(t, off, 64);
        float ex = fast_exp8(t);
        f32x2 ex2 = {ex, ex};
        den += ex;
        sxa += a;           sxb += b;             // pk add
        ssqa += a * a;      ssqb += b * b;        // pk fma
        smea += ex2 * a;    smeb += ex2 * b;      // pk fma
    };

    for (int base = s; base < e; base += 64) {    // chunk of <=64 edges
        int cnt = min(e - base, 64);
        // one coalesced load: lane holds srcs[base+lane] (clamped)
        int idx = srcs[base + min(lane, cnt - 1)];
        int p = 0;
        int2 da, db;
        if (p + 8 <= cnt) {                       // prologue: loads for batch 0
            int ra = __shfl(idx, p + g, 64);
            int rb = __shfl(idx, p + 4 + g, 64);
            da = xb2[(size_t)ra * 16 + q];
            db = xb2[(size_t)rb * 16 + q];
        }
        for (; p + 16 <= cnt; p += 8) {           // steady state: prefetch next
            int ra1 = __shfl(idx, p + 8 + g, 64);
            int rb1 = __shfl(idx, p + 12 + g, 64);
            int2 da1 = xb2[(size_t)ra1 * 16 + q];
            int2 db1 = xb2[(size_t)rb1 * 16 + q];
            compute(da);
            compute(db);
            da = da1; db = db1;
        }
        if (p + 8 <= cnt) {                       // drain
            compute(da);
            compute(db);
            p += 8;
        }
        if (p + 4 <= cnt) {
            int r = __shfl(idx, p + g, 64);
            compute(xb2[(size_t)r * 16 + q]);
            p += 4;
        }
        if (p < cnt) {                            // masked tail (1-3 edges)
            float wt = (p + g < cnt) ? 1.f : 0.f;
            int r = __shfl(idx, min(p + g, cnt - 1), 64);
            int2 d = xb2[(size_t)r * 16 + q];
            f32x2 a = {bflo(d.x), bfhi(d.x)};
            f32x2 b = {bflo(d.y), bfhi(d.y)};
            f32x2 dp = a * xn01 + b * xn23;
            float t = dp.x + dp.y;
            #pragma unroll
            for (int off = 1; off < 16; off <<= 1) t += __shfl_xor(t, off, 64);
            float ex = fast_exp8(t) * wt;
            f32x2 wt2 = {wt, wt}, ex2 = {ex, ex};
            f32x2 wa = a * wt2, wb = b * wt2;
            den += ex;
            sxa += wa;          sxb += wb;
            ssqa += wa * a;     ssqb += wb * b;
            smea += ex2 * a;    smeb += ex2 * b;
        }
    }
    // combine the 4 groups (lanes q, q+16, q+32, q+48 hold the same features)
    #pragma unroll
    for (int off = 16; off < 64; off <<= 1) {
        den    += __shfl_xor(den,    off, 64);
        sxa.x  += __shfl_xor(sxa.x,  off, 64); sxa.y  += __shfl_xor(sxa.y,  off, 64);
        sxb.x  += __shfl_xor(sxb.x,  off, 64); sxb.y  += __shfl_xor(sxb.y,  off, 64);
        ssqa.x += __shfl_xor(ssqa.x, off, 64); ssqa.y += __shfl_xor(ssqa.y, off, 64);
        ssqb.x += __shfl_xor(ssqb.x, off, 64); ssqb.y += __shfl_xor(ssqb.y, off, 64);
        smea.x += __shfl_xor(smea.x, off, 64); smea.y += __shfl_xor(smea.y, off, 64);
        smeb.x += __shfl_xor(smeb.x, off, 64); smeb.y += __shfl_xor(smeb.y, off, 64);
    }
    if (lane < 16) {
        float inv = 1.f / fmaxf((float)(e - s), 1.f);
        float invden = (den > 0.f) ? (1.f / den) : 0.f;
        float m0 = sxa.x * inv, m1 = sxa.y * inv, m2 = sxb.x * inv, m3 = sxb.y * inv;
        ushort4 hm, hv;
        hm.x = f2bf(smea.x * invden); hm.y = f2bf(smea.y * invden);
        hm.z = f2bf(smeb.x * invden); hm.w = f2bf(smeb.y * invden);
        hv.x = f2bf(ssqa.x * inv - m0 * m0); hv.y = f2bf(ssqa.y * inv - m1 * m1);
        hv.z = f2bf(ssqb.x * inv - m2 * m2); hv.w = f2bf(ssqb.y * inv - m3 * m3);
        *(ushort4*)&msgvar[(size_t)w * 128 + 4 * q]      = hm;
        *(ushort4*)&msgvar[(size_t)w * 128 + 64 + 4 * q] = hv;
    }
}

// MFMA epilogue GEMM: out = A @ Wcat^T + b, A = [x | msg | var] (N x 192),
// all inputs already bf16 (xb, msgvar). 2 node-tiles of 64 per block with
// W-fragments and bias resident in registers across tiles.
__global__ void __launch_bounds__(256) gemm_kernel(
        const unsigned short* __restrict__ xb, const unsigned short* __restrict__ msgvar,
        const float* __restrict__ Ws, const float* __restrict__ bs,
        const float* __restrict__ Wn, const float* __restrict__ bn,
        const float* __restrict__ Wv, const float* __restrict__ bv,
        float* __restrict__ out, int N) {
    __shared__ unsigned short As[64 * 200];
    int tid = threadIdx.x;
    int lane = tid & 63;
    int wv = tid >> 6;                  // feature tile (wave id)
    int j = lane & 15, quad = lane >> 4;
    int jg = wv * 16 + j;               // global output feature

    // B fragments: 6 K-steps, lane holds W[jg][k0..k0+7] as bf16
    const float* Wm0[3] = {Ws, Wn, Wv};
    bf16x8 bfrag[6];
    #pragma unroll
    for (int ks = 0; ks < 6; ++ks) {
        const float* W = Wm0[ks >> 1];
        int k0 = (ks & 1) * 32 + quad * 8;
        const float4* p = (const float4*)(W + (size_t)jg * 64 + k0);
        float4 a = p[0], b = p[1];
        bf16x8 f;
        f[0] = (short)f2bf(a.x); f[1] = (short)f2bf(a.y);
        f[2] = (short)f2bf(a.z); f[3] = (short)f2bf(a.w);
        f[4] = (short)f2bf(b.x); f[5] = (short)f2bf(b.y);
        f[6] = (short)f2bf(b.z); f[7] = (short)f2bf(b.w);
        bfrag[ks] = f;
    }
    float bias = bs[jg] + bn[jg] + bv[jg];

    #pragma unroll
    for (int t = 0; t < 2; ++t) {
        int nbase = blockIdx.x * 128 + t * 64;
        // stage x part from xb: 64 rows x 16 ushort4 (bf16 direct copy)
        #pragma unroll
        for (int i = 0; i < 4; ++i) {
            int idx = i * 256 + tid;
            int row = idx >> 4, c = idx & 15;
            int n = min(nbase + row, N - 1);
            ushort4 h = ((const ushort4*)(xb + (size_t)n * 64))[c];
            *(ushort4*)&As[row * 200 + c * 4] = h;
        }
        // stage msgvar part: 64 rows x 32 ushort4 (bf16, [msg|var] contiguous)
        #pragma unroll
        for (int i = 0; i < 8; ++i) {
            int idx = i * 256 + tid;
            int row = idx >> 5, c = idx & 31;
            int n = min(nbase + row, N - 1);
            ushort4 h = ((const ushort4*)(msgvar + (size_t)n * 128))[c];
            *(ushort4*)&As[row * 200 + 64 + c * 4] = h;
        }
        __syncthreads();

        f32x4 acc[4];
        #pragma unroll
        for (int nt = 0; nt < 4; ++nt) {
            acc[nt][0] = bias; acc[nt][1] = bias; acc[nt][2] = bias; acc[nt][3] = bias;
        }
        #pragma unroll
        for (int nt = 0; nt < 4; ++nt) {
            #pragma unroll
            for (int ks = 0; ks < 6; ++ks) {
                const bf16x8* ap = (const bf16x8*)&As[(nt * 16 + j) * 200 + ks * 32 + quad * 8];
                acc[nt] = __builtin_amdgcn_mfma_f32_16x16x32_bf16(*ap, bfrag[ks], acc[nt], 0, 0, 0);
            }
        }
        // D: node = nbase + nt*16 + quad*4 + r, col = jg
        #pragma unroll
        for (int nt = 0; nt < 4; ++nt) {
            #pragma unroll
            for (int r = 0; r < 4; ++r) {
                int node = nbase + nt * 16 + quad * 4 + r;
                if (node < N) out[(size_t)node * 64 + jg] = acc[nt][r];
            }
        }
        __syncthreads();   // protect As before next tile's staging
    }
}

extern "C" void kernel_launch(void* const* d_in, const int* in_sizes, int n_in,
                              void* d_out, int out_size, void* d_ws, size_t ws_size,
                              hipStream_t stream) {
    const float* x  = (const float*)d_in[0];
    const int*   ei = (const int*)d_in[1];
    const float* Ws = (const float*)d_in[2];
    const float* bs = (const float*)d_in[3];
    const float* Wn = (const float*)d_in[4];
    const float* bn = (const float*)d_in[5];
    const float* Wv = (const float*)d_in[6];
    const float* bv = (const float*)d_in[7];
    float* out = (float*)d_out;

    int N  = in_sizes[0] / 64;
    int E  = in_sizes[1] / 2;
    int nblk = (E + ECHUNK - 1) / ECHUNK;        // edge chunks (hist blocks)
    int nb1  = (N + 255) >> 8;                   // coarse buckets (<= 512)
    int M    = nb1 * nblk;                       // scan length
    int NBs  = (M + 255) / 256;                  // scan_a blocks (<= 1024)

    char* wsp = (char*)d_ws;
    size_t off = 0;
    int* hist   = (int*)(wsp + off); off += ws_align((size_t)M * 4);
    int* bsumi  = (int*)(wsp + off); off += ws_align((size_t)NBs * 4);
    int* rs     = (int*)(wsp + off); off += ws_align((size_t)(N + 1) * 4);
    int* tmp    = (int*)(wsp + off); off += ws_align((size_t)E * 4);
    int* srcs   = (int*)(wsp + off); off += ws_align((size_t)E * 4);
    unsigned short* msgvar = (unsigned short*)(wsp + off); off += ws_align((size_t)N * 128 * 2);
    unsigned short* xb     = (unsigned short*)(wsp + off); off += ws_align((size_t)N * 64 * 2);

    int n4 = N * 16;
    hist_cast_kernel<<<nblk, 256, 0, stream>>>(x, xb, ei, hist, E, n4, nblk, nb1);
    scan_a_kernel<<<NBs, 256, 0, stream>>>(hist, bsumi, M);
    scan_b_kernel<<<1, 1024, 0, stream>>>(bsumi, NBs);
    part_kernel<<<nblk, 256, 0, stream>>>(ei, hist, bsumi, tmp, E, nblk, nb1);
    fsort_kernel<<<nb1, 256, 0, stream>>>(tmp, hist, bsumi, srcs, rs, E, N, nblk, nb1);
    node_gather_kernel<<<((size_t)N * 64 + 255) / 256, 256, 0, stream>>>(xb, rs, srcs, msgvar, N);
    gemm_kernel<<<(N + 127) / 128, 256, 0, stream>>>(xb, msgvar, Ws, bs, Wn, bn, Wv, bv, out, N);
}

// Round 4
// 207.303 us; speedup vs baseline: 1.0573x; 1.0573x over previous
//
#include <hip/hip_runtime.h>

// RAConv: reciprocal-attention graph conv, N=100K nodes, E=1.6M edges, D=64, fp32.
// CSR build -> wave-per-node register gather -> bf16 MFMA GEMM.
//   msg = (sum_e x_src*exp(logit)) / (sum_e exp(logit));  var = E[x^2]-E[x]^2
// R2-R10: see git log. R11: global-atomic-free CSR (2-level LDS bucket sort).
// R12: srcs reg-preload + shfl, xb double-buffer (NEUTRAL -> gather is
//      VALU-issue-bound at 19.5 busy cy/edge, not latency-bound).
// R13: DPP reduce + ECHUNK 2048 (FAILED TO COMPILE: update_dpp ctrl must be
//      an integer-constant-expression; runtime param rejected by clang).
// R14: same plan, DPP helper as template<int CTRL> (true ICE):
//      (a) DPP-fused 16-lane dot reduce (quad_perm xor1/xor2 + row_ror 4/8,
//          4 VALU issues vs 8 ds_swizzle+add, frees LDS pipe);
//      (b) ECHUNK 4096->2048: hist/part occupancy 1.5->3 blocks/CU;
//      (c) scan_b carry-loop.

static inline size_t ws_align(size_t x) { return (x + 255) & ~size_t(255); }

typedef __attribute__((ext_vector_type(8))) short bf16x8;
typedef __attribute__((ext_vector_type(4))) float f32x4;
typedef __attribute__((ext_vector_type(2))) float f32x2;

#define ECHUNK 2048   // edges per histogram/partition block

__device__ __forceinline__ unsigned short f2bf(float f) {
    unsigned u = __builtin_bit_cast(unsigned, f);
    u += 0x7FFFu + ((u >> 16) & 1u);          // RNE
    return (unsigned short)(u >> 16);
}
__device__ __forceinline__ float bfhi(int d) {          // high bf16 of dword
    return __builtin_bit_cast(float, (unsigned)d & 0xFFFF0000u);
}
__device__ __forceinline__ float bflo(int d) {          // low bf16 of dword
    return __builtin_bit_cast(float, (unsigned)d << 16);
}

// sum across each 16-lane row via DPP (VALU pipe only):
// quad_perm xor1 (0xB1), quad_perm xor2 (0x4E) -> per-quad sums;
// row_ror:4 (0x124), row_ror:8 (0x128) -> sum the 4 quads; all lanes get total.
template <int CTRL>
__device__ __forceinline__ float dpp_radd(float t) {
    int v = __builtin_amdgcn_update_dpp(0, __builtin_bit_cast(int, t),
                                        CTRL, 0xF, 0xF, true);
    return t + __builtin_bit_cast(float, v);
}
__device__ __forceinline__ float row16_sum(float t) {
    t = dpp_radd<0xB1>(t);
    t = dpp_radd<0x4E>(t);
    t = dpp_radd<0x124>(t);
    t = dpp_radd<0x128>(t);
    return t;
}

// Fused: cast x->bf16 (grid-stride) AND per-chunk LDS histogram over coarse
// buckets (dst>>8). Block b owns edges [b*ECHUNK, (b+1)*ECHUNK); writes
// hist[bucket*nblk + b] (bucket-major so bucket segments are contiguous
// after the scan). No global atomics.
__global__ void __launch_bounds__(256) hist_cast_kernel(
        const float* __restrict__ x, unsigned short* __restrict__ xb,
        const int* __restrict__ ei, int* __restrict__ hist,
        int E, int n4, int nblk, int nb1) {
    __shared__ int h[512];                       // nb1 <= 512 (N <= 131072)
    for (int k = threadIdx.x; k < nb1; k += 256) h[k] = 0;
    // cast part: grid-stride over n4 float4s
    int stride = gridDim.x * 256;
    for (int i = blockIdx.x * 256 + threadIdx.x; i < n4; i += stride) {
        float4 v = ((const float4*)x)[i];
        ushort4 hh; hh.x = f2bf(v.x); hh.y = f2bf(v.y); hh.z = f2bf(v.z); hh.w = f2bf(v.w);
        ((ushort4*)xb)[i] = hh;
    }
    __syncthreads();
    const int* dstp = ei + E;
    int base = blockIdx.x * ECHUNK;
    #pragma unroll 4
    for (int k = 0; k < ECHUNK / 256; ++k) {
        int e = base + k * 256 + threadIdx.x;
        if (e < E) atomicAdd(&h[dstp[e] >> 8], 1);
    }
    __syncthreads();
    for (int k = threadIdx.x; k < nb1; k += 256) hist[k * nblk + blockIdx.x] = h[k];
}

// Exclusive scan over M = nb1*nblk counts, in place, 256/block; block sums out.
__global__ void scan_a_kernel(int* __restrict__ h, int* __restrict__ bsum, int M) {
    __shared__ int t[256];
    int i = blockIdx.x * 256 + threadIdx.x;
    int v = (i < M) ? h[i] : 0;
    t[threadIdx.x] = v;
    __syncthreads();
    for (int off = 1; off < 256; off <<= 1) {
        int u = (threadIdx.x >= (unsigned)off) ? t[threadIdx.x - off] : 0;
        __syncthreads();
        t[threadIdx.x] += u;
        __syncthreads();
    }
    if (i < M) h[i] = t[threadIdx.x] - v;        // exclusive within block
    if (threadIdx.x == 255) bsum[blockIdx.x] = t[255];
}

// Exclusive scan of block sums; carry loop supports any nb (1024 per round).
__global__ void scan_b_kernel(int* __restrict__ bsum, int nb) {
    __shared__ int t[1024];
    __shared__ int carry;
    if (threadIdx.x == 0) carry = 0;
    __syncthreads();
    for (int base = 0; base < nb; base += 1024) {
        int i = base + threadIdx.x;
        int v = (i < nb) ? bsum[i] : 0;
        t[threadIdx.x] = v;
        __syncthreads();
        for (int off = 1; off < 1024; off <<= 1) {
            int u = (threadIdx.x >= off) ? t[threadIdx.x - off] : 0;
            __syncthreads();
            t[threadIdx.x] += u;
            __syncthreads();
        }
        int c = carry;
        if (i < nb) bsum[i] = t[threadIdx.x] - v + c;   // exclusive + carry
        __syncthreads();
        if (threadIdx.x == 1023) carry = c + t[1023];
        __syncthreads();
    }
}

// Partition edges into coarse-bucket segments. Block b re-reads its chunk,
// ranks via LDS atomics on its scanned offsets, writes packed
// (src<<8)|(dst&255) -- src < 2^17, key 8 bits -> fits int.
__global__ void __launch_bounds__(256) part_kernel(
        const int* __restrict__ ei, const int* __restrict__ offs,
        const int* __restrict__ bsum, int* __restrict__ tmp,
        int E, int nblk, int nb1) {
    __shared__ int lofs[512];
    int b = blockIdx.x;
    for (int k = threadIdx.x; k < nb1; k += 256) {
        int idx = k * nblk + b;
        lofs[k] = offs[idx] + bsum[idx >> 8];
    }
    __syncthreads();
    const int* dstp = ei + E;
    int base = b * ECHUNK;
    #pragma unroll 4
    for (int k = 0; k < ECHUNK / 256; ++k) {
        int e = base + k * 256 + threadIdx.x;
        if (e < E) {
            int dst = dstp[e];
            int src = ei[e];
            int pos = atomicAdd(&lofs[dst >> 8], 1);
            tmp[pos] = (src << 8) | (dst & 255);
        }
    }
}

// Per-bucket fine sort: one block per bucket (256 nodes <-> 256 threads).
// LDS 256-bin hist + scan -> writes rs[node] directly, scatters srcs in CSR
// order via LDS-atomic ranks.
__global__ void __launch_bounds__(256) fsort_kernel(
        const int* __restrict__ tmp, const int* __restrict__ offs,
        const int* __restrict__ bsum, int* __restrict__ srcs,
        int* __restrict__ rs, int E, int N, int nblk, int nb1) {
    __shared__ int cnt[256], sc[256], lofs[256];
    int b = blockIdx.x, tid = threadIdx.x;
    int i0 = b * nblk;
    int start = offs[i0] + bsum[i0 >> 8];
    int end;
    if (b == nb1 - 1) end = E;
    else { int i1 = (b + 1) * nblk; end = offs[i1] + bsum[i1 >> 8]; }

    cnt[tid] = 0;
    __syncthreads();
    for (int e = start + tid; e < end; e += 256) atomicAdd(&cnt[tmp[e] & 255], 1);
    __syncthreads();
    int c = cnt[tid];
    sc[tid] = c;
    __syncthreads();
    for (int off = 1; off < 256; off <<= 1) {
        int u = (tid >= off) ? sc[tid - off] : 0;
        __syncthreads();
        sc[tid] += u;
        __syncthreads();
    }
    int excl = sc[tid] - c;
    int node = b * 256 + tid;
    if (node < N) rs[node] = start + excl;
    lofs[tid] = start + excl;
    __syncthreads();
    for (int e = start + tid; e < end; e += 256) {
        int v = tmp[e];
        int pos = atomicAdd(&lofs[v & 255], 1);
        srcs[pos] = v >> 8;
    }
    if (b == 0 && tid == 0) rs[N] = E;
}

// One wave per node, 4 edges per batch: 16-lane group g handles one edge,
// lane q=lane&15 holds features 4q..4q+3 as two float2 (packed-fp32 path).
// srcs preloaded 64/chunk into lane regs, batch indices via __shfl; xb row
// gathers double-buffered one batch ahead; dot reduce via DPP (R14).
__global__ void __launch_bounds__(256) node_gather_kernel(
        const unsigned short* __restrict__ xb,
        const int* __restrict__ rs, const int* __restrict__ srcs,
        unsigned short* __restrict__ msgvar, int N) {
    int w = (blockIdx.x * blockDim.x + threadIdx.x) >> 6;
    if (w >= N) return;
    int lane = threadIdx.x & 63;
    int q = lane & 15;                 // feature block (features 4q..4q+3)
    int g = lane >> 4;                 // edge slot within batch of 4
    int s = rs[w], e = rs[w + 1];
    const int2* xb2 = (const int2*)xb;            // row = 16 int2 (128 B)
    int2 dn = xb2[(size_t)w * 16 + q];
    f32x2 xn01 = {bflo(dn.x), bfhi(dn.x)}, xn23 = {bflo(dn.y), bfhi(dn.y)};
    float den = 0.f;
    f32x2 sxa = {0,0}, sxb = {0,0}, ssqa = {0,0}, ssqb = {0,0},
          smea = {0,0}, smeb = {0,0};

    auto compute = [&](int2 d) {
        f32x2 a = {bflo(d.x), bfhi(d.x)};
        f32x2 b = {bflo(d.y), bfhi(d.y)};
        f32x2 dp = a * xn01 + b * xn23;           // pk mul + pk fma
        float t = row16_sum(dp.x + dp.y);         // DPP reduce, VALU-only
        float ex = __expf(t * 0.125f);
        f32x2 ex2 = {ex, ex};
        den += ex;
        sxa += a;           sxb += b;             // pk add
        ssqa += a * a;      ssqb += b * b;        // pk fma
        smea += ex2 * a;    smeb += ex2 * b;      // pk fma
    };

    for (int base = s; base < e; base += 64) {    // chunk of <=64 edges
        int cnt = min(e - base, 64);
        // one coalesced load: lane holds srcs[base+lane] (clamped)
        int idx = srcs[base + min(lane, cnt - 1)];
        int p = 0;
        int2 da, db;
        if (p + 8 <= cnt) {                       // prologue: loads for batch 0
            int ra = __shfl(idx, p + g, 64);
            int rb = __shfl(idx, p + 4 + g, 64);
            da = xb2[(size_t)ra * 16 + q];
            db = xb2[(size_t)rb * 16 + q];
        }
        for (; p + 16 <= cnt; p += 8) {           // steady state: prefetch next
            int ra1 = __shfl(idx, p + 8 + g, 64);
            int rb1 = __shfl(idx, p + 12 + g, 64);
            int2 da1 = xb2[(size_t)ra1 * 16 + q];
            int2 db1 = xb2[(size_t)rb1 * 16 + q];
            compute(da);
            compute(db);
            da = da1; db = db1;
        }
        if (p + 8 <= cnt) {                       // drain
            compute(da);
            compute(db);
            p += 8;
        }
        if (p + 4 <= cnt) {
            int r = __shfl(idx, p + g, 64);
            compute(xb2[(size_t)r * 16 + q]);
            p += 4;
        }
        if (p < cnt) {                            // masked tail (1-3 edges)
            float wt = (p + g < cnt) ? 1.f : 0.f;
            int r = __shfl(idx, min(p + g, cnt - 1), 64);
            int2 d = xb2[(size_t)r * 16 + q];
            f32x2 a = {bflo(d.x), bfhi(d.x)};
            f32x2 b = {bflo(d.y), bfhi(d.y)};
            f32x2 dp = a * xn01 + b * xn23;
            float t = row16_sum(dp.x + dp.y);
            float ex = __expf(t * 0.125f) * wt;
            f32x2 wt2 = {wt, wt}, ex2 = {ex, ex};
            f32x2 wa = a * wt2, wb = b * wt2;
            den += ex;
            sxa += wa;          sxb += wb;
            ssqa += wa * a;     ssqb += wb * b;
            smea += ex2 * a;    smeb += ex2 * b;
        }
    }
    // combine the 4 groups (lanes q, q+16, q+32, q+48 hold the same features)
    #pragma unroll
    for (int off = 16; off < 64; off <<= 1) {
        den    += __shfl_xor(den,    off, 64);
        sxa.x  += __shfl_xor(sxa.x,  off, 64); sxa.y  += __shfl_xor(sxa.y,  off, 64);
        sxb.x  += __shfl_xor(sxb.x,  off, 64); sxb.y  += __shfl_xor(sxb.y,  off, 64);
        ssqa.x += __shfl_xor(ssqa.x, off, 64); ssqa.y += __shfl_xor(ssqa.y, off, 64);
        ssqb.x += __shfl_xor(ssqb.x, off, 64); ssqb.y += __shfl_xor(ssqb.y, off, 64);
        smea.x += __shfl_xor(smea.x, off, 64); smea.y += __shfl_xor(smea.y, off, 64);
        smeb.x += __shfl_xor(smeb.x, off, 64); smeb.y += __shfl_xor(smeb.y, off, 64);
    }
    if (lane < 16) {
        float inv = 1.f / fmaxf((float)(e - s), 1.f);
        float invden = (den > 0.f) ? (1.f / den) : 0.f;
        float m0 = sxa.x * inv, m1 = sxa.y * inv, m2 = sxb.x * inv, m3 = sxb.y * inv;
        ushort4 hm, hv;
        hm.x = f2bf(smea.x * invden); hm.y = f2bf(smea.y * invden);
        hm.z = f2bf(smeb.x * invden); hm.w = f2bf(smeb.y * invden);
        hv.x = f2bf(ssqa.x * inv - m0 * m0); hv.y = f2bf(ssqa.y * inv - m1 * m1);
        hv.z = f2bf(ssqb.x * inv - m2 * m2); hv.w = f2bf(ssqb.y * inv - m3 * m3);
        *(ushort4*)&msgvar[(size_t)w * 128 + 4 * q]      = hm;
        *(ushort4*)&msgvar[(size_t)w * 128 + 64 + 4 * q] = hv;
    }
}

// MFMA epilogue GEMM: out = A @ Wcat^T + b, A = [x | msg | var] (N x 192),
// all inputs already bf16 (xb, msgvar). 2 node-tiles of 64 per block with
// W-fragments and bias resident in registers across tiles.
__global__ void __launch_bounds__(256) gemm_kernel(
        const unsigned short* __restrict__ xb, const unsigned short* __restrict__ msgvar,
        const float* __restrict__ Ws, const float* __restrict__ bs,
        const float* __restrict__ Wn, const float* __restrict__ bn,
        const float* __restrict__ Wv, const float* __restrict__ bv,
        float* __restrict__ out, int N) {
    __shared__ unsigned short As[64 * 200];
    int tid = threadIdx.x;
    int lane = tid & 63;
    int wv = tid >> 6;                  // feature tile (wave id)
    int j = lane & 15, quad = lane >> 4;
    int jg = wv * 16 + j;               // global output feature

    // B fragments: 6 K-steps, lane holds W[jg][k0..k0+7] as bf16
    const float* Wm0[3] = {Ws, Wn, Wv};
    bf16x8 bfrag[6];
    #pragma unroll
    for (int ks = 0; ks < 6; ++ks) {
        const float* W = Wm0[ks >> 1];
        int k0 = (ks & 1) * 32 + quad * 8;
        const float4* p = (const float4*)(W + (size_t)jg * 64 + k0);
        float4 a = p[0], b = p[1];
        bf16x8 f;
        f[0] = (short)f2bf(a.x); f[1] = (short)f2bf(a.y);
        f[2] = (short)f2bf(a.z); f[3] = (short)f2bf(a.w);
        f[4] = (short)f2bf(b.x); f[5] = (short)f2bf(b.y);
        f[6] = (short)f2bf(b.z); f[7] = (short)f2bf(b.w);
        bfrag[ks] = f;
    }
    float bias = bs[jg] + bn[jg] + bv[jg];

    #pragma unroll
    for (int t = 0; t < 2; ++t) {
        int nbase = blockIdx.x * 128 + t * 64;
        // stage x part from xb: 64 rows x 16 ushort4 (bf16 direct copy)
        #pragma unroll
        for (int i = 0; i < 4; ++i) {
            int idx = i * 256 + tid;
            int row = idx >> 4, c = idx & 15;
            int n = min(nbase + row, N - 1);
            ushort4 h = ((const ushort4*)(xb + (size_t)n * 64))[c];
            *(ushort4*)&As[row * 200 + c * 4] = h;
        }
        // stage msgvar part: 64 rows x 32 ushort4 (bf16, [msg|var] contiguous)
        #pragma unroll
        for (int i = 0; i < 8; ++i) {
            int idx = i * 256 + tid;
            int row = idx >> 5, c = idx & 31;
            int n = min(nbase + row, N - 1);
            ushort4 h = ((const ushort4*)(msgvar + (size_t)n * 128))[c];
            *(ushort4*)&As[row * 200 + 64 + c * 4] = h;
        }
        __syncthreads();

        f32x4 acc[4];
        #pragma unroll
        for (int nt = 0; nt < 4; ++nt) {
            acc[nt][0] = bias; acc[nt][1] = bias; acc[nt][2] = bias; acc[nt][3] = bias;
        }
        #pragma unroll
        for (int nt = 0; nt < 4; ++nt) {
            #pragma unroll
            for (int ks = 0; ks < 6; ++ks) {
                const bf16x8* ap = (const bf16x8*)&As[(nt * 16 + j) * 200 + ks * 32 + quad * 8];
                acc[nt] = __builtin_amdgcn_mfma_f32_16x16x32_bf16(*ap, bfrag[ks], acc[nt], 0, 0, 0);
            }
        }
        // D: node = nbase + nt*16 + quad*4 + r, col = jg
        #pragma unroll
        for (int nt = 0; nt < 4; ++nt) {
            #pragma unroll
            for (int r = 0; r < 4; ++r) {
                int node = nbase + nt * 16 + quad * 4 + r;
                if (node < N) out[(size_t)node * 64 + jg] = acc[nt][r];
            }
        }
        __syncthreads();   // protect As before next tile's staging
    }
}

extern "C" void kernel_launch(void* const* d_in, const int* in_sizes, int n_in,
                              void* d_out, int out_size, void* d_ws, size_t ws_size,
                              hipStream_t stream) {
    const float* x  = (const float*)d_in[0];
    const int*   ei = (const int*)d_in[1];
    const float* Ws = (const float*)d_in[2];
    const float* bs = (const float*)d_in[3];
    const float* Wn = (const float*)d_in[4];
    const float* bn = (const float*)d_in[5];
    const float* Wv = (const float*)d_in[6];
    const float* bv = (const float*)d_in[7];
    float* out = (float*)d_out;

    int N  = in_sizes[0] / 64;
    int E  = in_sizes[1] / 2;
    int nblk = (E + ECHUNK - 1) / ECHUNK;        // edge chunks (hist blocks)
    int nb1  = (N + 255) >> 8;                   // coarse buckets (<= 512)
    int M    = nb1 * nblk;                       // scan length
    int NBs  = (M + 255) / 256;                  // scan_a blocks

    char* wsp = (char*)d_ws;
    size_t off = 0;
    int* hist   = (int*)(wsp + off); off += ws_align((size_t)M * 4);
    int* bsumi  = (int*)(wsp + off); off += ws_align((size_t)NBs * 4);
    int* rs     = (int*)(wsp + off); off += ws_align((size_t)(N + 1) * 4);
    int* tmp    = (int*)(wsp + off); off += ws_align((size_t)E * 4);
    int* srcs   = (int*)(wsp + off); off += ws_align((size_t)E * 4);
    unsigned short* msgvar = (unsigned short*)(wsp + off); off += ws_align((size_t)N * 128 * 2);
    unsigned short* xb     = (unsigned short*)(wsp + off); off += ws_align((size_t)N * 64 * 2);

    int n4 = N * 16;
    hist_cast_kernel<<<nblk, 256, 0, stream>>>(x, xb, ei, hist, E, n4, nblk, nb1);
    scan_a_kernel<<<NBs, 256, 0, stream>>>(hist, bsumi, M);
    scan_b_kernel<<<1, 1024, 0, stream>>>(bsumi, NBs);
    part_kernel<<<nblk, 256, 0, stream>>>(ei, hist, bsumi, tmp, E, nblk, nb1);
    fsort_kernel<<<nb1, 256, 0, stream>>>(tmp, hist, bsumi, srcs, rs, E, N, nblk, nb1);
    node_gather_kernel<<<((size_t)N * 64 + 255) / 256, 256, 0, stream>>>(xb, rs, srcs, msgvar, N);
    gemm_kernel<<<(N + 127) / 128, 256, 0, stream>>>(xb, msgvar, Ws, bs, Wn, bn, Wv, bv, out, N);
}

// Round 6
// 198.209 us; speedup vs baseline: 1.1058x; 1.0459x over previous
//
#include <hip/hip_runtime.h>

// RAConv: reciprocal-attention graph conv, N=100K nodes, E=1.6M edges, D=64, fp32.
// CSR build -> wave-per-node register gather -> bf16 MFMA GEMM.
//   msg = (sum_e x_src*exp(logit)) / (sum_e exp(logit));  var = E[x^2]-E[x]^2
// R2-R10: see git log. R11: global-atomic-free CSR (2-level LDS bucket sort).
// R12: srcs reg-preload + shfl (NEUTRAL -> gather VALU-issue-bound).
// R13: FAILED COMPILE (update_dpp ctrl must be ICE).
// R14: DPP 16-lane dot reduce: gather 68->54us (matched pred).
// R15: FAILED CORRECTNESS (absmax 9.3): combine4 used permlane16/32_swap with
//      SAME value for both operands -> two-output swap degenerates to in-place
//      permute, r[0]+r[1] = 2*permuted(u), group sums wrong. permlane swap
//      is only valid with two DISTINCT operands (T12 usage).
// R16: revert combine4 to shfl_xor(^16,^32) (R14-proven); KEEP the R15 CSR
//      improvements: ECHUNK 4096, 512-thread hist/part/fsort (2x waves/CU),
//      fsort single-pass LDS staging (saves one 6.4MB tmp re-read),
//      merged masked tail in gather.

static inline size_t ws_align(size_t x) { return (x + 255) & ~size_t(255); }

typedef __attribute__((ext_vector_type(8))) short bf16x8;
typedef __attribute__((ext_vector_type(4))) float f32x4;
typedef __attribute__((ext_vector_type(2))) float f32x2;

#define ECHUNK 4096   // edges per histogram/partition block
#define FCAP   5120   // fsort LDS staging capacity (avg seg 4096, max ~4400)

__device__ __forceinline__ unsigned short f2bf(float f) {
    unsigned u = __builtin_bit_cast(unsigned, f);
    u += 0x7FFFu + ((u >> 16) & 1u);          // RNE
    return (unsigned short)(u >> 16);
}
__device__ __forceinline__ float bfhi(int d) {          // high bf16 of dword
    return __builtin_bit_cast(float, (unsigned)d & 0xFFFF0000u);
}
__device__ __forceinline__ float bflo(int d) {          // low bf16 of dword
    return __builtin_bit_cast(float, (unsigned)d << 16);
}

// sum across each 16-lane row via DPP (VALU pipe only):
// quad_perm xor1 (0xB1), quad_perm xor2 (0x4E) -> per-quad sums;
// row_ror:4 (0x124), row_ror:8 (0x128) -> sum the 4 quads; all lanes get total.
template <int CTRL>
__device__ __forceinline__ float dpp_radd(float t) {
    int v = __builtin_amdgcn_update_dpp(0, __builtin_bit_cast(int, t),
                                        CTRL, 0xF, 0xF, true);
    return t + __builtin_bit_cast(float, v);
}
__device__ __forceinline__ float row16_sum(float t) {
    t = dpp_radd<0xB1>(t);
    t = dpp_radd<0x4E>(t);
    t = dpp_radd<0x124>(t);
    t = dpp_radd<0x128>(t);
    return t;
}

// sum across the 4 16-lane groups (R14-proven shfl path; permlane-swap with
// identical operands is INVALID -- see R15 note).
__device__ __forceinline__ float combine4(float t) {
    t += __shfl_xor(t, 16, 64);
    t += __shfl_xor(t, 32, 64);
    return t;
}

// Fused: cast x->bf16 (grid-stride) AND per-chunk LDS histogram over coarse
// buckets (dst>>8). Block b owns edges [b*ECHUNK, (b+1)*ECHUNK); writes
// hist[bucket*nblk + b] (bucket-major). No global atomics. 512 threads.
__global__ void __launch_bounds__(512) hist_cast_kernel(
        const float* __restrict__ x, unsigned short* __restrict__ xb,
        const int* __restrict__ ei, int* __restrict__ hist,
        int E, int n4, int nblk, int nb1) {
    __shared__ int h[512];                       // nb1 <= 512 (N <= 131072)
    int tid = threadIdx.x;
    for (int k = tid; k < nb1; k += 512) h[k] = 0;
    // cast part: grid-stride over n4 float4s
    int stride = gridDim.x * 512;
    for (int i = blockIdx.x * 512 + tid; i < n4; i += stride) {
        float4 v = ((const float4*)x)[i];
        ushort4 hh; hh.x = f2bf(v.x); hh.y = f2bf(v.y); hh.z = f2bf(v.z); hh.w = f2bf(v.w);
        ((ushort4*)xb)[i] = hh;
    }
    __syncthreads();
    const int* dstp = ei + E;
    int base = blockIdx.x * ECHUNK;
    #pragma unroll 4
    for (int k = 0; k < ECHUNK / 512; ++k) {
        int e = base + k * 512 + tid;
        if (e < E) atomicAdd(&h[dstp[e] >> 8], 1);
    }
    __syncthreads();
    for (int k = tid; k < nb1; k += 512) hist[k * nblk + blockIdx.x] = h[k];
}

// Exclusive scan over M = nb1*nblk counts, in place, 256/block; block sums out.
__global__ void scan_a_kernel(int* __restrict__ h, int* __restrict__ bsum, int M) {
    __shared__ int t[256];
    int i = blockIdx.x * 256 + threadIdx.x;
    int v = (i < M) ? h[i] : 0;
    t[threadIdx.x] = v;
    __syncthreads();
    for (int off = 1; off < 256; off <<= 1) {
        int u = (threadIdx.x >= (unsigned)off) ? t[threadIdx.x - off] : 0;
        __syncthreads();
        t[threadIdx.x] += u;
        __syncthreads();
    }
    if (i < M) h[i] = t[threadIdx.x] - v;        // exclusive within block
    if (threadIdx.x == 255) bsum[blockIdx.x] = t[255];
}

// Exclusive scan of block sums; carry loop supports any nb (1024 per round).
__global__ void scan_b_kernel(int* __restrict__ bsum, int nb) {
    __shared__ int t[1024];
    __shared__ int carry;
    if (threadIdx.x == 0) carry = 0;
    __syncthreads();
    for (int base = 0; base < nb; base += 1024) {
        int i = base + threadIdx.x;
        int v = (i < nb) ? bsum[i] : 0;
        t[threadIdx.x] = v;
        __syncthreads();
        for (int off = 1; off < 1024; off <<= 1) {
            int u = (threadIdx.x >= off) ? t[threadIdx.x - off] : 0;
            __syncthreads();
            t[threadIdx.x] += u;
            __syncthreads();
        }
        int c = carry;
        if (i < nb) bsum[i] = t[threadIdx.x] - v + c;   // exclusive + carry
        __syncthreads();
        if (threadIdx.x == 1023) carry = c + t[1023];
        __syncthreads();
    }
}

// Partition edges into coarse-bucket segments. Block b re-reads its chunk,
// ranks via LDS atomics on its scanned offsets, writes packed
// (src<<8)|(dst&255) -- src < 2^17, key 8 bits -> fits int. 512 threads.
__global__ void __launch_bounds__(512) part_kernel(
        const int* __restrict__ ei, const int* __restrict__ offs,
        const int* __restrict__ bsum, int* __restrict__ tmp,
        int E, int nblk, int nb1) {
    __shared__ int lofs[512];
    int b = blockIdx.x, tid = threadIdx.x;
    for (int k = tid; k < nb1; k += 512) {
        int idx = k * nblk + b;
        lofs[k] = offs[idx] + bsum[idx >> 8];
    }
    __syncthreads();
    const int* dstp = ei + E;
    int base = b * ECHUNK;
    #pragma unroll 4
    for (int k = 0; k < ECHUNK / 512; ++k) {
        int e = base + k * 512 + tid;
        if (e < E) {
            int dst = dstp[e];
            int src = ei[e];
            int pos = atomicAdd(&lofs[dst >> 8], 1);
            tmp[pos] = (src << 8) | (dst & 255);
        }
    }
}

// Per-bucket fine sort: one block per bucket (256 nodes), 512 threads.
// Segment staged once into LDS (<=FCAP edges); hist + rank-scatter read
// LDS instead of streaming tmp twice from global. Fallback if oversized.
__global__ void __launch_bounds__(512) fsort_kernel(
        const int* __restrict__ tmp, const int* __restrict__ offs,
        const int* __restrict__ bsum, int* __restrict__ srcs,
        int* __restrict__ rs, int E, int N, int nblk, int nb1) {
    __shared__ int cnt[256], sc[256], lofs[256];
    __shared__ int stage[FCAP];
    int b = blockIdx.x, tid = threadIdx.x;
    int i0 = b * nblk;
    int start = offs[i0] + bsum[i0 >> 8];
    int end;
    if (b == nb1 - 1) end = E;
    else { int i1 = (b + 1) * nblk; end = offs[i1] + bsum[i1 >> 8]; }
    int seg = end - start;
    bool fit = (seg <= FCAP);                    // block-uniform

    if (tid < 256) cnt[tid] = 0;
    if (fit) for (int k = tid; k < seg; k += 512) stage[k] = tmp[start + k];
    __syncthreads();
    if (fit) for (int k = tid; k < seg; k += 512) atomicAdd(&cnt[stage[k] & 255], 1);
    else     for (int e = start + tid; e < end; e += 512) atomicAdd(&cnt[tmp[e] & 255], 1);
    __syncthreads();
    int c = (tid < 256) ? cnt[tid] : 0;
    if (tid < 256) sc[tid] = c;
    __syncthreads();
    for (int off = 1; off < 256; off <<= 1) {
        int u = (tid < 256 && tid >= off) ? sc[tid - off] : 0;
        __syncthreads();
        if (tid < 256) sc[tid] += u;
        __syncthreads();
    }
    if (tid < 256) {
        int excl = sc[tid] - c;
        int node = b * 256 + tid;
        if (node < N) rs[node] = start + excl;
        lofs[tid] = start + excl;
    }
    __syncthreads();
    if (fit) {
        for (int k = tid; k < seg; k += 512) {
            int v = stage[k];
            int pos = atomicAdd(&lofs[v & 255], 1);
            srcs[pos] = v >> 8;
        }
    } else {
        for (int e = start + tid; e < end; e += 512) {
            int v = tmp[e];
            int pos = atomicAdd(&lofs[v & 255], 1);
            srcs[pos] = v >> 8;
        }
    }
    if (b == 0 && tid == 0) rs[N] = E;
}

// One wave per node, 4 edges per batch: 16-lane group g handles one edge,
// lane q=lane&15 holds features 4q..4q+3 as two float2 (packed-fp32 path).
// srcs preloaded 64/chunk into lane regs, batch indices via __shfl; xb row
// gathers double-buffered one batch ahead; dot reduce via DPP; group combine
// via shfl_xor; single masked tail loop.
__global__ void __launch_bounds__(256) node_gather_kernel(
        const unsigned short* __restrict__ xb,
        const int* __restrict__ rs, const int* __restrict__ srcs,
        unsigned short* __restrict__ msgvar, int N) {
    int w = (blockIdx.x * blockDim.x + threadIdx.x) >> 6;
    if (w >= N) return;
    int lane = threadIdx.x & 63;
    int q = lane & 15;                 // feature block (features 4q..4q+3)
    int g = lane >> 4;                 // edge slot within batch of 4
    int s = rs[w], e = rs[w + 1];
    const int2* xb2 = (const int2*)xb;            // row = 16 int2 (128 B)
    int2 dn = xb2[(size_t)w * 16 + q];
    f32x2 xn01 = {bflo(dn.x), bfhi(dn.x)}, xn23 = {bflo(dn.y), bfhi(dn.y)};
    float den = 0.f;
    f32x2 sxa = {0,0}, sxb = {0,0}, ssqa = {0,0}, ssqb = {0,0},
          smea = {0,0}, smeb = {0,0};

    auto compute = [&](int2 d) {
        f32x2 a = {bflo(d.x), bfhi(d.x)};
        f32x2 b = {bflo(d.y), bfhi(d.y)};
        f32x2 dp = a * xn01 + b * xn23;           // pk mul + pk fma
        float t = row16_sum(dp.x + dp.y);         // DPP reduce, VALU-only
        float ex = __expf(t * 0.125f);
        f32x2 ex2 = {ex, ex};
        den += ex;
        sxa += a;           sxb += b;             // pk add
        ssqa += a * a;      ssqb += b * b;        // pk fma
        smea += ex2 * a;    smeb += ex2 * b;      // pk fma
    };

    for (int base = s; base < e; base += 64) {    // chunk of <=64 edges
        int cnt = min(e - base, 64);
        // one coalesced load: lane holds srcs[base+lane] (clamped)
        int idx = srcs[base + min(lane, cnt - 1)];
        int p = 0;
        int2 da, db;
        if (p + 8 <= cnt) {                       // prologue: loads for batch 0
            int ra = __shfl(idx, p + g, 64);
            int rb = __shfl(idx, p + 4 + g, 64);
            da = xb2[(size_t)ra * 16 + q];
            db = xb2[(size_t)rb * 16 + q];
        }
        for (; p + 16 <= cnt; p += 8) {           // steady state: prefetch next
            int ra1 = __shfl(idx, p + 8 + g, 64);
            int rb1 = __shfl(idx, p + 12 + g, 64);
            int2 da1 = xb2[(size_t)ra1 * 16 + q];
            int2 db1 = xb2[(size_t)rb1 * 16 + q];
            compute(da);
            compute(db);
            da = da1; db = db1;
        }
        if (p + 8 <= cnt) {                       // drain
            compute(da);
            compute(db);
            p += 8;
        }
        for (; p < cnt; p += 4) {                 // masked tail (<=2 iters)
            float wt = (p + g < cnt) ? 1.f : 0.f;
            int r = __shfl(idx, min(p + g, cnt - 1), 64);
            int2 d = xb2[(size_t)r * 16 + q];
            f32x2 a = {bflo(d.x), bfhi(d.x)};
            f32x2 b = {bflo(d.y), bfhi(d.y)};
            f32x2 dp = a * xn01 + b * xn23;
            float t = row16_sum(dp.x + dp.y);
            float ex = __expf(t * 0.125f) * wt;
            f32x2 wt2 = {wt, wt}, ex2 = {ex, ex};
            f32x2 wa = a * wt2, wb = b * wt2;
            den += ex;
            sxa += wa;          sxb += wb;
            ssqa += wa * a;     ssqb += wb * b;
            smea += ex2 * a;    smeb += ex2 * b;
        }
    }
    // combine the 4 groups (lanes q, q+16, q+32, q+48 hold the same features)
    den    = combine4(den);
    sxa.x  = combine4(sxa.x);  sxa.y  = combine4(sxa.y);
    sxb.x  = combine4(sxb.x);  sxb.y  = combine4(sxb.y);
    ssqa.x = combine4(ssqa.x); ssqa.y = combine4(ssqa.y);
    ssqb.x = combine4(ssqb.x); ssqb.y = combine4(ssqb.y);
    smea.x = combine4(smea.x); smea.y = combine4(smea.y);
    smeb.x = combine4(smeb.x); smeb.y = combine4(smeb.y);
    if (lane < 16) {
        float inv = 1.f / fmaxf((float)(e - s), 1.f);
        float invden = (den > 0.f) ? (1.f / den) : 0.f;
        float m0 = sxa.x * inv, m1 = sxa.y * inv, m2 = sxb.x * inv, m3 = sxb.y * inv;
        ushort4 hm, hv;
        hm.x = f2bf(smea.x * invden); hm.y = f2bf(smea.y * invden);
        hm.z = f2bf(smeb.x * invden); hm.w = f2bf(smeb.y * invden);
        hv.x = f2bf(ssqa.x * inv - m0 * m0); hv.y = f2bf(ssqa.y * inv - m1 * m1);
        hv.z = f2bf(ssqb.x * inv - m2 * m2); hv.w = f2bf(ssqb.y * inv - m3 * m3);
        *(ushort4*)&msgvar[(size_t)w * 128 + 4 * q]      = hm;
        *(ushort4*)&msgvar[(size_t)w * 128 + 64 + 4 * q] = hv;
    }
}

// MFMA epilogue GEMM: out = A @ Wcat^T + b, A = [x | msg | var] (N x 192),
// all inputs already bf16 (xb, msgvar). 2 node-tiles of 64 per block with
// W-fragments and bias resident in registers across tiles.
__global__ void __launch_bounds__(256) gemm_kernel(
        const unsigned short* __restrict__ xb, const unsigned short* __restrict__ msgvar,
        const float* __restrict__ Ws, const float* __restrict__ bs,
        const float* __restrict__ Wn, const float* __restrict__ bn,
        const float* __restrict__ Wv, const float* __restrict__ bv,
        float* __restrict__ out, int N) {
    __shared__ unsigned short As[64 * 200];
    int tid = threadIdx.x;
    int lane = tid & 63;
    int wv = tid >> 6;                  // feature tile (wave id)
    int j = lane & 15, quad = lane >> 4;
    int jg = wv * 16 + j;               // global output feature

    // B fragments: 6 K-steps, lane holds W[jg][k0..k0+7] as bf16
    const float* Wm0[3] = {Ws, Wn, Wv};
    bf16x8 bfrag[6];
    #pragma unroll
    for (int ks = 0; ks < 6; ++ks) {
        const float* W = Wm0[ks >> 1];
        int k0 = (ks & 1) * 32 + quad * 8;
        const float4* p = (const float4*)(W + (size_t)jg * 64 + k0);
        float4 a = p[0], b = p[1];
        bf16x8 f;
        f[0] = (short)f2bf(a.x); f[1] = (short)f2bf(a.y);
        f[2] = (short)f2bf(a.z); f[3] = (short)f2bf(a.w);
        f[4] = (short)f2bf(b.x); f[5] = (short)f2bf(b.y);
        f[6] = (short)f2bf(b.z); f[7] = (short)f2bf(b.w);
        bfrag[ks] = f;
    }
    float bias = bs[jg] + bn[jg] + bv[jg];

    #pragma unroll
    for (int t = 0; t < 2; ++t) {
        int nbase = blockIdx.x * 128 + t * 64;
        // stage x part from xb: 64 rows x 16 ushort4 (bf16 direct copy)
        #pragma unroll
        for (int i = 0; i < 4; ++i) {
            int idx = i * 256 + tid;
            int row = idx >> 4, c = idx & 15;
            int n = min(nbase + row, N - 1);
            ushort4 h = ((const ushort4*)(xb + (size_t)n * 64))[c];
            *(ushort4*)&As[row * 200 + c * 4] = h;
        }
        // stage msgvar part: 64 rows x 32 ushort4 (bf16, [msg|var] contiguous)
        #pragma unroll
        for (int i = 0; i < 8; ++i) {
            int idx = i * 256 + tid;
            int row = idx >> 5, c = idx & 31;
            int n = min(nbase + row, N - 1);
            ushort4 h = ((const ushort4*)(msgvar + (size_t)n * 128))[c];
            *(ushort4*)&As[row * 200 + 64 + c * 4] = h;
        }
        __syncthreads();

        f32x4 acc[4];
        #pragma unroll
        for (int nt = 0; nt < 4; ++nt) {
            acc[nt][0] = bias; acc[nt][1] = bias; acc[nt][2] = bias; acc[nt][3] = bias;
        }
        #pragma unroll
        for (int nt = 0; nt < 4; ++nt) {
            #pragma unroll
            for (int ks = 0; ks < 6; ++ks) {
                const bf16x8* ap = (const bf16x8*)&As[(nt * 16 + j) * 200 + ks * 32 + quad * 8];
                acc[nt] = __builtin_amdgcn_mfma_f32_16x16x32_bf16(*ap, bfrag[ks], acc[nt], 0, 0, 0);
            }
        }
        // D: node = nbase + nt*16 + quad*4 + r, col = jg
        #pragma unroll
        for (int nt = 0; nt < 4; ++nt) {
            #pragma unroll
            for (int r = 0; r < 4; ++r) {
                int node = nbase + nt * 16 + quad * 4 + r;
                if (node < N) out[(size_t)node * 64 + jg] = acc[nt][r];
            }
        }
        __syncthreads();   // protect As before next tile's staging
    }
}

extern "C" void kernel_launch(void* const* d_in, const int* in_sizes, int n_in,
                              void* d_out, int out_size, void* d_ws, size_t ws_size,
                              hipStream_t stream) {
    const float* x  = (const float*)d_in[0];
    const int*   ei = (const int*)d_in[1];
    const float* Ws = (const float*)d_in[2];
    const float* bs = (const float*)d_in[3];
    const float* Wn = (const float*)d_in[4];
    const float* bn = (const float*)d_in[5];
    const float* Wv = (const float*)d_in[6];
    const float* bv = (const float*)d_in[7];
    float* out = (float*)d_out;

    int N  = in_sizes[0] / 64;
    int E  = in_sizes[1] / 2;
    int nblk = (E + ECHUNK - 1) / ECHUNK;        // edge chunks (hist blocks)
    int nb1  = (N + 255) >> 8;                   // coarse buckets (<= 512)
    int M    = nb1 * nblk;                       // scan length
    int NBs  = (M + 255) / 256;                  // scan_a blocks

    char* wsp = (char*)d_ws;
    size_t off = 0;
    int* hist   = (int*)(wsp + off); off += ws_align((size_t)M * 4);
    int* bsumi  = (int*)(wsp + off); off += ws_align((size_t)NBs * 4);
    int* rs     = (int*)(wsp + off); off += ws_align((size_t)(N + 1) * 4);
    int* tmp    = (int*)(wsp + off); off += ws_align((size_t)E * 4);
    int* srcs   = (int*)(wsp + off); off += ws_align((size_t)E * 4);
    unsigned short* msgvar = (unsigned short*)(wsp + off); off += ws_align((size_t)N * 128 * 2);
    unsigned short* xb     = (unsigned short*)(wsp + off); off += ws_align((size_t)N * 64 * 2);

    int n4 = N * 16;
    hist_cast_kernel<<<nblk, 512, 0, stream>>>(x, xb, ei, hist, E, n4, nblk, nb1);
    scan_a_kernel<<<NBs, 256, 0, stream>>>(hist, bsumi, M);
    scan_b_kernel<<<1, 1024, 0, stream>>>(bsumi, NBs);
    part_kernel<<<nblk, 512, 0, stream>>>(ei, hist, bsumi, tmp, E, nblk, nb1);
    fsort_kernel<<<nb1, 512, 0, stream>>>(tmp, hist, bsumi, srcs, rs, E, N, nblk, nb1);
    node_gather_kernel<<<((size_t)N * 64 + 255) / 256, 256, 0, stream>>>(xb, rs, srcs, msgvar, N);
    gemm_kernel<<<(N + 127) / 128, 256, 0, stream>>>(xb, msgvar, Ws, bs, Wn, bn, Wv, bv, out, N);
}

// Round 7
// 194.218 us; speedup vs baseline: 1.1285x; 1.0205x over previous
//
#include <hip/hip_runtime.h>

// RAConv: reciprocal-attention graph conv, N=100K nodes, E=1.6M edges, D=64, fp32.
// CSR build -> wave-per-node register gather -> bf16 MFMA GEMM.
//   msg = (sum_e x_src*exp(logit)) / (sum_e exp(logit));  var = E[x^2]-E[x]^2
// R11: global-atomic-free CSR (2-level LDS bucket sort).
// R12: srcs reg-preload + shfl (NEUTRAL -> gather VALU-issue-bound).
// R14: DPP 16-lane dot reduce: gather 68->54us (matched pred).
// R15: FAILED: permlane16/32_swap with identical operands is an in-place
//      permute, NOT a reduce. Reverted in R16 (shfl_xor combine).
// R16: 512-thread CSR kernels + fsort LDS staging: 198us. Others=143.7us
//      vs ~80us traffic bound -> overhead is kernel count (5-dispatch CSR
//      build, single-block scan_b serializer, extra edge pass, gaps).
// R17: CSR build collapsed 5 kernels -> 2 via block-aggregated atomic
//      reservation into PADDED bucket segments (CAP=5120; bucket load
//      4096+-64, max~4350=12sigma under CAP):
//        build: LDS count -> 1 atomicAdd/bucket/block (153K total, vs R0's
//               1.6M per-edge = 70us) -> scatter to tmp[b*CAP + base + rank].
//        fsort: bounds from gcnt; writes explicit rs/re (padded srcs is not
//               globally contiguous). No scan_a/scan_b/hist, one less edge
//               pass, 3 fewer dispatch gaps.

static inline size_t ws_align(size_t x) { return (x + 255) & ~size_t(255); }

typedef __attribute__((ext_vector_type(8))) short bf16x8;
typedef __attribute__((ext_vector_type(4))) float f32x4;
typedef __attribute__((ext_vector_type(2))) float f32x2;

#define ECHUNK 4096   // edges per build block
#define CAP    5120   // padded per-bucket capacity (and fsort LDS staging)

__device__ __forceinline__ unsigned short f2bf(float f) {
    unsigned u = __builtin_bit_cast(unsigned, f);
    u += 0x7FFFu + ((u >> 16) & 1u);          // RNE
    return (unsigned short)(u >> 16);
}
__device__ __forceinline__ float bfhi(int d) {          // high bf16 of dword
    return __builtin_bit_cast(float, (unsigned)d & 0xFFFF0000u);
}
__device__ __forceinline__ float bflo(int d) {          // low bf16 of dword
    return __builtin_bit_cast(float, (unsigned)d << 16);
}

// sum across each 16-lane row via DPP (VALU pipe only):
// quad_perm xor1 (0xB1), quad_perm xor2 (0x4E) -> per-quad sums;
// row_ror:4 (0x124), row_ror:8 (0x128) -> sum the 4 quads; all lanes get total.
template <int CTRL>
__device__ __forceinline__ float dpp_radd(float t) {
    int v = __builtin_amdgcn_update_dpp(0, __builtin_bit_cast(int, t),
                                        CTRL, 0xF, 0xF, true);
    return t + __builtin_bit_cast(float, v);
}
__device__ __forceinline__ float row16_sum(float t) {
    t = dpp_radd<0xB1>(t);
    t = dpp_radd<0x4E>(t);
    t = dpp_radd<0x124>(t);
    t = dpp_radd<0x128>(t);
    return t;
}

// sum across the 4 16-lane groups (R14-proven; permlane-swap with identical
// operands is INVALID -- see R15 note).
__device__ __forceinline__ float combine4(float t) {
    t += __shfl_xor(t, 16, 64);
    t += __shfl_xor(t, 32, 64);
    return t;
}

// Fused: cast x->bf16 (grid-stride) AND one-pass bucket partition with
// block-aggregated reservation. Per block: LDS count over dst>>8, then one
// global atomicAdd per bucket reserves [base, base+cnt) within the bucket's
// padded segment, then scatter packed (src<<8)|(dst&255) to
// tmp[b*CAP + base + local_rank]. gcnt must be pre-zeroed.
__global__ void __launch_bounds__(512) build_kernel(
        const float* __restrict__ x, unsigned short* __restrict__ xb,
        const int* __restrict__ ei, int* __restrict__ gcnt,
        int* __restrict__ tmp, int E, int n4, int nb1) {
    __shared__ int cnt[512];                     // nb1 <= 512 (N <= 131072)
    __shared__ int base[512];
    int tid = threadIdx.x;
    for (int k = tid; k < nb1; k += 512) cnt[k] = 0;
    // cast part: grid-stride over n4 float4s
    int stride = gridDim.x * 512;
    for (int i = blockIdx.x * 512 + tid; i < n4; i += stride) {
        float4 v = ((const float4*)x)[i];
        ushort4 hh; hh.x = f2bf(v.x); hh.y = f2bf(v.y); hh.z = f2bf(v.z); hh.w = f2bf(v.w);
        ((ushort4*)xb)[i] = hh;
    }
    __syncthreads();
    const int* dstp = ei + E;
    int cbase = blockIdx.x * ECHUNK;
    #pragma unroll 4
    for (int k = 0; k < ECHUNK / 512; ++k) {
        int e = cbase + k * 512 + tid;
        if (e < E) atomicAdd(&cnt[dstp[e] >> 8], 1);
    }
    __syncthreads();
    for (int k = tid; k < nb1; k += 512) {
        int c = cnt[k];
        base[k] = c ? atomicAdd(&gcnt[k], c) : 0;   // block-level reservation
        cnt[k] = 0;                                  // reuse as rank counter
    }
    __syncthreads();
    #pragma unroll 4
    for (int k = 0; k < ECHUNK / 512; ++k) {
        int e = cbase + k * 512 + tid;
        if (e < E) {
            int dst = dstp[e];
            int b = dst >> 8;
            int r = base[b] + atomicAdd(&cnt[b], 1);
            if (r < CAP)                             // overflow guard (never hit)
                tmp[b * CAP + r] = (ei[e] << 8) | (dst & 255);
        }
    }
}

// Per-bucket fine sort: one block per bucket (256 nodes), 512 threads.
// Segment [b*CAP, b*CAP+gcnt[b]) staged once into LDS; 256-bin hist + scan
// -> writes per-node bounds rs/re, scatters srcs in node order.
__global__ void __launch_bounds__(512) fsort_kernel(
        const int* __restrict__ tmp, const int* __restrict__ gcnt,
        int* __restrict__ srcs, int* __restrict__ rs, int* __restrict__ re,
        int N, int nb1) {
    __shared__ int cnt[256], sc[256], lofs[256];
    __shared__ int stage[CAP];
    int b = blockIdx.x, tid = threadIdx.x;
    int start = b * CAP;
    int seg = min(gcnt[b], CAP);

    if (tid < 256) cnt[tid] = 0;
    for (int k = tid; k < seg; k += 512) stage[k] = tmp[start + k];
    __syncthreads();
    for (int k = tid; k < seg; k += 512) atomicAdd(&cnt[stage[k] & 255], 1);
    __syncthreads();
    int c = (tid < 256) ? cnt[tid] : 0;
    if (tid < 256) sc[tid] = c;
    __syncthreads();
    for (int off = 1; off < 256; off <<= 1) {
        int u = (tid < 256 && tid >= off) ? sc[tid - off] : 0;
        __syncthreads();
        if (tid < 256) sc[tid] += u;
        __syncthreads();
    }
    if (tid < 256) {
        int excl = sc[tid] - c;
        int node = b * 256 + tid;
        if (node < N) { rs[node] = start + excl; re[node] = start + excl + c; }
        lofs[tid] = start + excl;
    }
    __syncthreads();
    for (int k = tid; k < seg; k += 512) {
        int v = stage[k];
        int pos = atomicAdd(&lofs[v & 255], 1);
        srcs[pos] = v >> 8;
    }
}

// One wave per node, 4 edges per batch: 16-lane group g handles one edge,
// lane q=lane&15 holds features 4q..4q+3 as two float2 (packed-fp32 path).
// srcs preloaded 64/chunk into lane regs, batch indices via __shfl; xb row
// gathers double-buffered one batch ahead; dot reduce via DPP; group combine
// via shfl_xor; single masked tail loop. Bounds from rs/re (padded CSR).
__global__ void __launch_bounds__(256) node_gather_kernel(
        const unsigned short* __restrict__ xb,
        const int* __restrict__ rs, const int* __restrict__ re,
        const int* __restrict__ srcs,
        unsigned short* __restrict__ msgvar, int N) {
    int w = (blockIdx.x * blockDim.x + threadIdx.x) >> 6;
    if (w >= N) return;
    int lane = threadIdx.x & 63;
    int q = lane & 15;                 // feature block (features 4q..4q+3)
    int g = lane >> 4;                 // edge slot within batch of 4
    int s = rs[w], e = re[w];
    const int2* xb2 = (const int2*)xb;            // row = 16 int2 (128 B)
    int2 dn = xb2[(size_t)w * 16 + q];
    f32x2 xn01 = {bflo(dn.x), bfhi(dn.x)}, xn23 = {bflo(dn.y), bfhi(dn.y)};
    float den = 0.f;
    f32x2 sxa = {0,0}, sxb = {0,0}, ssqa = {0,0}, ssqb = {0,0},
          smea = {0,0}, smeb = {0,0};

    auto compute = [&](int2 d) {
        f32x2 a = {bflo(d.x), bfhi(d.x)};
        f32x2 b = {bflo(d.y), bfhi(d.y)};
        f32x2 dp = a * xn01 + b * xn23;           // pk mul + pk fma
        float t = row16_sum(dp.x + dp.y);         // DPP reduce, VALU-only
        float ex = __expf(t * 0.125f);
        f32x2 ex2 = {ex, ex};
        den += ex;
        sxa += a;           sxb += b;             // pk add
        ssqa += a * a;      ssqb += b * b;        // pk fma
        smea += ex2 * a;    smeb += ex2 * b;      // pk fma
    };

    for (int base = s; base < e; base += 64) {    // chunk of <=64 edges
        int cnt = min(e - base, 64);
        // one coalesced load: lane holds srcs[base+lane] (clamped)
        int idx = srcs[base + min(lane, cnt - 1)];
        int p = 0;
        int2 da, db;
        if (p + 8 <= cnt) {                       // prologue: loads for batch 0
            int ra = __shfl(idx, p + g, 64);
            int rb = __shfl(idx, p + 4 + g, 64);
            da = xb2[(size_t)ra * 16 + q];
            db = xb2[(size_t)rb * 16 + q];
        }
        for (; p + 16 <= cnt; p += 8) {           // steady state: prefetch next
            int ra1 = __shfl(idx, p + 8 + g, 64);
            int rb1 = __shfl(idx, p + 12 + g, 64);
            int2 da1 = xb2[(size_t)ra1 * 16 + q];
            int2 db1 = xb2[(size_t)rb1 * 16 + q];
            compute(da);
            compute(db);
            da = da1; db = db1;
        }
        if (p + 8 <= cnt) {                       // drain
            compute(da);
            compute(db);
            p += 8;
        }
        for (; p < cnt; p += 4) {                 // masked tail (<=2 iters)
            float wt = (p + g < cnt) ? 1.f : 0.f;
            int r = __shfl(idx, min(p + g, cnt - 1), 64);
            int2 d = xb2[(size_t)r * 16 + q];
            f32x2 a = {bflo(d.x), bfhi(d.x)};
            f32x2 b = {bflo(d.y), bfhi(d.y)};
            f32x2 dp = a * xn01 + b * xn23;
            float t = row16_sum(dp.x + dp.y);
            float ex = __expf(t * 0.125f) * wt;
            f32x2 wt2 = {wt, wt}, ex2 = {ex, ex};
            f32x2 wa = a * wt2, wb = b * wt2;
            den += ex;
            sxa += wa;          sxb += wb;
            ssqa += wa * a;     ssqb += wb * b;
            smea += ex2 * a;    smeb += ex2 * b;
        }
    }
    // combine the 4 groups (lanes q, q+16, q+32, q+48 hold the same features)
    den    = combine4(den);
    sxa.x  = combine4(sxa.x);  sxa.y  = combine4(sxa.y);
    sxb.x  = combine4(sxb.x);  sxb.y  = combine4(sxb.y);
    ssqa.x = combine4(ssqa.x); ssqa.y = combine4(ssqa.y);
    ssqb.x = combine4(ssqb.x); ssqb.y = combine4(ssqb.y);
    smea.x = combine4(smea.x); smea.y = combine4(smea.y);
    smeb.x = combine4(smeb.x); smeb.y = combine4(smeb.y);
    if (lane < 16) {
        float inv = 1.f / fmaxf((float)(e - s), 1.f);
        float invden = (den > 0.f) ? (1.f / den) : 0.f;
        float m0 = sxa.x * inv, m1 = sxa.y * inv, m2 = sxb.x * inv, m3 = sxb.y * inv;
        ushort4 hm, hv;
        hm.x = f2bf(smea.x * invden); hm.y = f2bf(smea.y * invden);
        hm.z = f2bf(smeb.x * invden); hm.w = f2bf(smeb.y * invden);
        hv.x = f2bf(ssqa.x * inv - m0 * m0); hv.y = f2bf(ssqa.y * inv - m1 * m1);
        hv.z = f2bf(ssqb.x * inv - m2 * m2); hv.w = f2bf(ssqb.y * inv - m3 * m3);
        *(ushort4*)&msgvar[(size_t)w * 128 + 4 * q]      = hm;
        *(ushort4*)&msgvar[(size_t)w * 128 + 64 + 4 * q] = hv;
    }
}

// MFMA epilogue GEMM: out = A @ Wcat^T + b, A = [x | msg | var] (N x 192),
// all inputs already bf16 (xb, msgvar). 2 node-tiles of 64 per block with
// W-fragments and bias resident in registers across tiles.
__global__ void __launch_bounds__(256) gemm_kernel(
        const unsigned short* __restrict__ xb, const unsigned short* __restrict__ msgvar,
        const float* __restrict__ Ws, const float* __restrict__ bs,
        const float* __restrict__ Wn, const float* __restrict__ bn,
        const float* __restrict__ Wv, const float* __restrict__ bv,
        float* __restrict__ out, int N) {
    __shared__ unsigned short As[64 * 200];
    int tid = threadIdx.x;
    int lane = tid & 63;
    int wv = tid >> 6;                  // feature tile (wave id)
    int j = lane & 15, quad = lane >> 4;
    int jg = wv * 16 + j;               // global output feature

    // B fragments: 6 K-steps, lane holds W[jg][k0..k0+7] as bf16
    const float* Wm0[3] = {Ws, Wn, Wv};
    bf16x8 bfrag[6];
    #pragma unroll
    for (int ks = 0; ks < 6; ++ks) {
        const float* W = Wm0[ks >> 1];
        int k0 = (ks & 1) * 32 + quad * 8;
        const float4* p = (const float4*)(W + (size_t)jg * 64 + k0);
        float4 a = p[0], b = p[1];
        bf16x8 f;
        f[0] = (short)f2bf(a.x); f[1] = (short)f2bf(a.y);
        f[2] = (short)f2bf(a.z); f[3] = (short)f2bf(a.w);
        f[4] = (short)f2bf(b.x); f[5] = (short)f2bf(b.y);
        f[6] = (short)f2bf(b.z); f[7] = (short)f2bf(b.w);
        bfrag[ks] = f;
    }
    float bias = bs[jg] + bn[jg] + bv[jg];

    #pragma unroll
    for (int t = 0; t < 2; ++t) {
        int nbase = blockIdx.x * 128 + t * 64;
        // stage x part from xb: 64 rows x 16 ushort4 (bf16 direct copy)
        #pragma unroll
        for (int i = 0; i < 4; ++i) {
            int idx = i * 256 + tid;
            int row = idx >> 4, c = idx & 15;
            int n = min(nbase + row, N - 1);
            ushort4 h = ((const ushort4*)(xb + (size_t)n * 64))[c];
            *(ushort4*)&As[row * 200 + c * 4] = h;
        }
        // stage msgvar part: 64 rows x 32 ushort4 (bf16, [msg|var] contiguous)
        #pragma unroll
        for (int i = 0; i < 8; ++i) {
            int idx = i * 256 + tid;
            int row = idx >> 5, c = idx & 31;
            int n = min(nbase + row, N - 1);
            ushort4 h = ((const ushort4*)(msgvar + (size_t)n * 128))[c];
            *(ushort4*)&As[row * 200 + 64 + c * 4] = h;
        }
        __syncthreads();

        f32x4 acc[4];
        #pragma unroll
        for (int nt = 0; nt < 4; ++nt) {
            acc[nt][0] = bias; acc[nt][1] = bias; acc[nt][2] = bias; acc[nt][3] = bias;
        }
        #pragma unroll
        for (int nt = 0; nt < 4; ++nt) {
            #pragma unroll
            for (int ks = 0; ks < 6; ++ks) {
                const bf16x8* ap = (const bf16x8*)&As[(nt * 16 + j) * 200 + ks * 32 + quad * 8];
                acc[nt] = __builtin_amdgcn_mfma_f32_16x16x32_bf16(*ap, bfrag[ks], acc[nt], 0, 0, 0);
            }
        }
        // D: node = nbase + nt*16 + quad*4 + r, col = jg
        #pragma unroll
        for (int nt = 0; nt < 4; ++nt) {
            #pragma unroll
            for (int r = 0; r < 4; ++r) {
                int node = nbase + nt * 16 + quad * 4 + r;
                if (node < N) out[(size_t)node * 64 + jg] = acc[nt][r];
            }
        }
        __syncthreads();   // protect As before next tile's staging
    }
}

extern "C" void kernel_launch(void* const* d_in, const int* in_sizes, int n_in,
                              void* d_out, int out_size, void* d_ws, size_t ws_size,
                              hipStream_t stream) {
    const float* x  = (const float*)d_in[0];
    const int*   ei = (const int*)d_in[1];
    const float* Ws = (const float*)d_in[2];
    const float* bs = (const float*)d_in[3];
    const float* Wn = (const float*)d_in[4];
    const float* bn = (const float*)d_in[5];
    const float* Wv = (const float*)d_in[6];
    const float* bv = (const float*)d_in[7];
    float* out = (float*)d_out;

    int N  = in_sizes[0] / 64;
    int E  = in_sizes[1] / 2;
    int nblk = (E + ECHUNK - 1) / ECHUNK;        // build blocks
    int nb1  = (N + 255) >> 8;                   // coarse buckets (<= 512)

    char* wsp = (char*)d_ws;
    size_t off = 0;
    int* gcnt   = (int*)(wsp + off); off += ws_align((size_t)nb1 * 4);
    int* rs     = (int*)(wsp + off); off += ws_align((size_t)N * 4);
    int* re     = (int*)(wsp + off); off += ws_align((size_t)N * 4);
    int* tmp    = (int*)(wsp + off); off += ws_align((size_t)nb1 * CAP * 4);
    int* srcs   = (int*)(wsp + off); off += ws_align((size_t)nb1 * CAP * 4);
    unsigned short* msgvar = (unsigned short*)(wsp + off); off += ws_align((size_t)N * 128 * 2);
    unsigned short* xb     = (unsigned short*)(wsp + off); off += ws_align((size_t)N * 64 * 2);

    int n4 = N * 16;
    hipMemsetAsync(gcnt, 0, (size_t)nb1 * 4, stream);
    build_kernel<<<nblk, 512, 0, stream>>>(x, xb, ei, gcnt, tmp, E, n4, nb1);
    fsort_kernel<<<nb1, 512, 0, stream>>>(tmp, gcnt, srcs, rs, re, N, nb1);
    node_gather_kernel<<<((size_t)N * 64 + 255) / 256, 256, 0, stream>>>(xb, rs, re, srcs, msgvar, N);
    gemm_kernel<<<(N + 127) / 128, 256, 0, stream>>>(xb, msgvar, Ws, bs, Wn, bn, Wv, bv, out, N);
}